// Round 4
// baseline (738.369 us; speedup 1.0000x reference)
//
#include <hip/hip_runtime.h>
#include <cstdint>
#include <cstddef>

#define NNODES 50000
#define HD 256
#define NCH 3
#define BM 64

typedef __attribute__((ext_vector_type(8))) short shortx8;
typedef __attribute__((ext_vector_type(4))) float floatx4;

__device__ __forceinline__ unsigned short f2bf(float x) {
    union { float f; uint32_t u; } v; v.f = x;
    uint32_t r = v.u + 0x7fffu + ((v.u >> 16) & 1u);   // round-to-nearest-even
    return (unsigned short)(r >> 16);
}
__device__ __forceinline__ float sigf(float x) {
    return 1.0f / (1.0f + __expf(-x));
}
__device__ __forceinline__ float tanhfast(float x) {
    return 1.0f - 2.0f / (__expf(2.0f * x) + 1.0f);
}
__device__ __forceinline__ floatx4 mfma16(shortx8 a, shortx8 b, floatx4 c) {
    return __builtin_amdgcn_mfma_f32_16x16x32_bf16(a, b, c, 0, 0, 0);
}

// ---------------------------------------------------------------------------
// Pre-pass: weights fp32 [out,in] -> bf16 MFMA B-fragments in d_ws.
// fi = ((d*64 + tile)*8 + ks)*64 + lane ; 8 bf16 each.
// tile 0..15 -> U_f cols; 16..31 -> I; 32..47 -> O; 48..63 -> U.
// elem e: k = ks*32 + (lane>>4)*8 + e, col = tile*16 + (lane&15)
// ---------------------------------------------------------------------------
__global__ void prep_weights(const float* __restrict__ U_f,
                             const float* __restrict__ U_iou,
                             unsigned short* __restrict__ wsB) {
    int idx = blockIdx.x * 256 + threadIdx.x;
    int lane = idx & 63;
    int ks   = (idx >> 6) & 7;
    int tile = (idx >> 9) & 63;
    int d    = idx >> 15;
    if (d >= NCH) return;
    int col = tile * 16 + (lane & 15);
    int k0  = ks * 32 + (lane >> 4) * 8;
    const float* src = (col < 256)
        ? (U_f   + (((size_t)d * 256 + col)         * 256 + k0))
        : (U_iou + (((size_t)d * 768 + (col - 256)) * 256 + k0));
    shortx8 o;
    #pragma unroll
    for (int e = 0; e < 8; ++e) o[e] = (short)f2bf(src[e]);
    reinterpret_cast<shortx8*>(wsB)[idx] = o;
}

// ---------------------------------------------------------------------------
// Main kernel: 1024 threads = 16 waves, BM=64 nodes, 96 KiB LDS (nh only).
// ONE barrier total. After it, wave w independently handles hidden-slice
// [w*16, w*16+16): F tile w (per child, fold in C-layout registers),
// IOU tiles {16+w, 32+w, 48+w} (K=768), epilogue in C-layout. No relayout
// buffer, no further syncs -> waves de-phase and overlap pipes.
// LDS layout: [d][slot][ node ^ (slot&7) ][8] bf16 (XOR kills the 32-way
// stage-write conflict; MFMA reads stay 256B-contiguous per 16-lane group).
// ---------------------------------------------------------------------------
__global__ __launch_bounds__(1024, 4) void treelstm_main(
    const float* __restrict__ nh,       // [N][3][256]
    const float* __restrict__ ncc,      // [N][3][256]
    const float* __restrict__ f_in,     // [N][256]
    const float* __restrict__ iou_in,   // [N][768]
    const unsigned short* __restrict__ wsB,
    float* __restrict__ out)            // h [N][256] then c [N][256]
{
    extern __shared__ unsigned short sA[];   // 3*32*64*8 = 49152 bf16 = 96 KiB

    const int tid  = threadIdx.x;
    const int nb   = blockIdx.x * BM;
    const int lane = tid & 63;
    const int w    = tid >> 6;        // 0..15: hidden-slice owner
    const int cl   = lane & 15;
    const int g    = lane >> 4;
    const int kcol = w * 16 + cl;     // this thread's hidden column

    const shortx8* Bfr = reinterpret_cast<const shortx8*>(wsB);

    // ---- stage nh (all children) fp32 -> bf16, coalesced reads,
    //      XOR-swizzled LDS writes ----
    #pragma unroll
    for (int i = 0; i < 6; ++i) {
        int c    = i * 1024 + tid;         // 0..6143
        int d    = c >> 11;
        int node = (c >> 5) & 63;
        int slot = c & 31;
        int gn   = nb + node;
        shortx8 o;
        if (gn < NNODES) {
            const float4* q = reinterpret_cast<const float4*>(
                nh + ((size_t)gn * (NCH * HD) + d * HD + slot * 8));
            float4 u0 = q[0], u1 = q[1];
            o[0] = (short)f2bf(u0.x); o[1] = (short)f2bf(u0.y);
            o[2] = (short)f2bf(u0.z); o[3] = (short)f2bf(u0.w);
            o[4] = (short)f2bf(u1.x); o[5] = (short)f2bf(u1.y);
            o[6] = (short)f2bf(u1.z); o[7] = (short)f2bf(u1.w);
        } else {
            #pragma unroll
            for (int e = 0; e < 8; ++e) o[e] = 0;
        }
        int idx = (d * 32 + slot) * 64 + (node ^ (slot & 7));
        *reinterpret_cast<shortx8*>(&sA[idx * 8]) = o;
    }
    __syncthreads();     // the ONLY barrier

    // ================= F phase (per child), fold in registers ==============
    float fin[16], cagg[16];
    #pragma unroll
    for (int t = 0; t < 16; ++t) cagg[t] = 0.0f;

    for (int d = 0; d < NCH; ++d) {
        float ncr[16];
        #pragma unroll
        for (int rt = 0; rt < 4; ++rt)
            #pragma unroll
            for (int r = 0; r < 4; ++r) {
                int n = nb + rt * 16 + g * 4 + r;
                int t = rt * 4 + r;
                ncr[t] = 0.0f;
                if (n < NNODES) {
                    ncr[t] = ncc[(size_t)n * (NCH * HD) + d * HD + kcol];
                    if (d == 0) fin[t] = f_in[(size_t)n * HD + kcol];
                    else if (d == 0) fin[t] = 0.0f;
                } else if (d == 0) fin[t] = 0.0f;
            }

        floatx4 accF[4];
        #pragma unroll
        for (int rt = 0; rt < 4; ++rt)
            #pragma unroll
            for (int e = 0; e < 4; ++e) accF[rt][e] = 0.0f;

        shortx8 bc = Bfr[((d * 64 + w) * 8 + 0) * 64 + lane];
        #pragma unroll
        for (int ks = 0; ks < 8; ++ks) {
            shortx8 bn = (ks < 7) ? Bfr[((d * 64 + w) * 8 + ks + 1) * 64 + lane] : bc;
            int s = ks * 4 + g;
            int x = s & 7;
            #pragma unroll
            for (int rt = 0; rt < 4; ++rt) {
                int ai = (d * 32 + s) * 64 + ((rt * 16 + cl) ^ x);
                shortx8 a = *reinterpret_cast<const shortx8*>(&sA[ai * 8]);
                accF[rt] = mfma16(a, bc, accF[rt]);
            }
            bc = bn;
        }

        #pragma unroll
        for (int rt = 0; rt < 4; ++rt)
            #pragma unroll
            for (int r = 0; r < 4; ++r) {
                int t = rt * 4 + r;
                cagg[t] += sigf(accF[rt][r] + fin[t]) * ncr[t];
            }
    }

    // ================= IOU GEMM: K=768, 1-deep B prefetch ==================
    floatx4 acc[4][3];
    #pragma unroll
    for (int rt = 0; rt < 4; ++rt)
        #pragma unroll
        for (int q = 0; q < 3; ++q)
            #pragma unroll
            for (int e = 0; e < 4; ++e) acc[rt][q][e] = 0.0f;

    shortx8 bc0 = Bfr[((16 + w) * 8 + 0) * 64 + lane];
    shortx8 bc1 = Bfr[((32 + w) * 8 + 0) * 64 + lane];
    shortx8 bc2 = Bfr[((48 + w) * 8 + 0) * 64 + lane];
    #pragma unroll
    for (int step = 0; step < 24; ++step) {
        int d  = step >> 3;
        int ks = step & 7;
        shortx8 bn0 = bc0, bn1 = bc1, bn2 = bc2;
        if (step < 23) {
            int sn  = step + 1;
            int dn  = sn >> 3;
            int ksn = sn & 7;
            bn0 = Bfr[((dn * 64 + 16 + w) * 8 + ksn) * 64 + lane];
            bn1 = Bfr[((dn * 64 + 32 + w) * 8 + ksn) * 64 + lane];
            bn2 = Bfr[((dn * 64 + 48 + w) * 8 + ksn) * 64 + lane];
        }
        int s = ks * 4 + g;
        int x = s & 7;
        shortx8 a0 = *reinterpret_cast<const shortx8*>(&sA[((d * 32 + s) * 64 + ((cl)      ^ x)) * 8]);
        shortx8 a1 = *reinterpret_cast<const shortx8*>(&sA[((d * 32 + s) * 64 + ((16 + cl) ^ x)) * 8]);
        shortx8 a2 = *reinterpret_cast<const shortx8*>(&sA[((d * 32 + s) * 64 + ((32 + cl) ^ x)) * 8]);
        shortx8 a3 = *reinterpret_cast<const shortx8*>(&sA[((d * 32 + s) * 64 + ((48 + cl) ^ x)) * 8]);
        __builtin_amdgcn_s_setprio(1);
        acc[0][0] = mfma16(a0, bc0, acc[0][0]);
        acc[1][0] = mfma16(a1, bc0, acc[1][0]);
        acc[2][0] = mfma16(a2, bc0, acc[2][0]);
        acc[3][0] = mfma16(a3, bc0, acc[3][0]);
        acc[0][1] = mfma16(a0, bc1, acc[0][1]);
        acc[1][1] = mfma16(a1, bc1, acc[1][1]);
        acc[2][1] = mfma16(a2, bc1, acc[2][1]);
        acc[3][1] = mfma16(a3, bc1, acc[3][1]);
        acc[0][2] = mfma16(a0, bc2, acc[0][2]);
        acc[1][2] = mfma16(a1, bc2, acc[1][2]);
        acc[2][2] = mfma16(a2, bc2, acc[2][2]);
        acc[3][2] = mfma16(a3, bc2, acc[3][2]);
        __builtin_amdgcn_s_setprio(0);
        bc0 = bn0; bc1 = bn1; bc2 = bn2;
    }

    // ================= epilogue, C-layout, no syncs ========================
    #pragma unroll
    for (int rt = 0; rt < 4; ++rt)
        #pragma unroll
        for (int r = 0; r < 4; ++r) {
            int n = nb + rt * 16 + g * 4 + r;
            if (n >= NNODES) continue;
            size_t ib = (size_t)n * 768 + kcol;
            float iv = acc[rt][0][r] + 2.0f * iou_in[ib];
            float ov = acc[rt][1][r] + 2.0f * iou_in[ib + 256];
            float uv = acc[rt][2][r] + 2.0f * iou_in[ib + 512];
            float cc = sigf(iv) * tanhfast(uv) + cagg[rt * 4 + r];
            float hh = sigf(ov) * tanhfast(cc);
            out[(size_t)n * HD + kcol] = hh;
            out[(size_t)(NNODES + n) * HD + kcol] = cc;
        }
}

extern "C" void kernel_launch(void* const* d_in, const int* in_sizes, int n_in,
                              void* d_out, int out_size, void* d_ws, size_t ws_size,
                              hipStream_t stream) {
    const float* nh     = (const float*)d_in[0];
    const float* ncc    = (const float*)d_in[1];
    const float* f_in   = (const float*)d_in[2];
    const float* iou_in = (const float*)d_in[3];
    const float* U_f    = (const float*)d_in[4];
    const float* U_iou  = (const float*)d_in[5];
    unsigned short* wsB = (unsigned short*)d_ws;

    if (ws_size < (size_t)(3 * 64 * 8 * 64) * 16) return;

    hipLaunchKernelGGL(prep_weights, dim3(384), dim3(256), 0, stream,
                       U_f, U_iou, wsB);
    hipLaunchKernelGGL(treelstm_main, dim3((NNODES + BM - 1) / BM), dim3(1024),
                       NCH * 32 * BM * 8 * sizeof(unsigned short), stream,
                       nh, ncc, f_in, iou_in, wsB, (float*)d_out);
}